// Round 1
// 405.833 us; speedup vs baseline: 1.0309x; 1.0309x over previous
//
#include <hip/hip_runtime.h>
#include <cstdint>

// ---------------------------------------------------------------------------
// DeepSpeedSelfAttention fused: LN -> QKV GEMM -> flash attention -> out proj
// B=4 S=2048 H=1024 HEADS=16 DHEAD=64. bf16 MFMA 16x16x32 everywhere.
// R4: k_attn was LDS-BW-bound (96 KB/block-kt, ~6.3 GB total ~ 91-120 us at
// LDS ceiling = the whole 130 us). Changes:
//   * QBLK 64 -> 128: each wave owns 32 q-rows (2x16 tiles) so K/V fragment
//     reads amortize over 2x rows (112 KB/block-kt for 2x work = 1.7x less).
//   * swapped QK^T (S^T = mfma(K, Q)): k lands on the C-register axis, so
//     P packs 4 k-consecutive bf16 -> one ds_write_b64 (4x fewer LDS write
//     ops), mask loads become float4. A/B frags of 16x16x32 are index-
//     identical per lane so the swap just transposes C.
//   * LDS 48 KiB (K/V dbuf 32K + 4x4K wave-private P) -> 3 blocks/CU.
// Outputs: [0] out_proj [1] key [2] value [3] context (f32 each).
// ---------------------------------------------------------------------------

typedef __attribute__((ext_vector_type(8))) short short8;
typedef __attribute__((ext_vector_type(4))) short short4v;
typedef __attribute__((ext_vector_type(4))) float floatx4;

#define BSH 8388608
#define PART_STRIDE 8388608
#define LOG2E 1.4426950408889634f

static __device__ __forceinline__ short f2bf(float f) {  // RNE
  union { float f; uint32_t u; } v; v.f = f;
  uint32_t r = v.u + 0x7fffu + ((v.u >> 16) & 1u);
  return (short)(r >> 16);
}
static __device__ __forceinline__ short f2bf_fast(float f) {  // round-half-up
  union { float f; uint32_t u; } v; v.f = f;
  return (short)((v.u + 0x8000u) >> 16);
}

// async global->LDS, width 16. LDS dest = wave-uniform base + lane*16.
typedef __attribute__((address_space(1))) void gas_t;
typedef __attribute__((address_space(3))) void las_t;
static __device__ __forceinline__ void async16(const void* g, const void* l) {
  __builtin_amdgcn_global_load_lds((gas_t*)(uintptr_t)g,
                                   (las_t*)(uint32_t)(uintptr_t)l, 16, 0, 0);
}

// ---- fp32 -> bf16 weight conversion ---------------------------------------
__global__ __launch_bounds__(256) void k_convert(const float4* __restrict__ wqkv,
                                                 const float4* __restrict__ ow,
                                                 short4v* __restrict__ dq,
                                                 short4v* __restrict__ dow) {
  const int n1 = (3072 * 1024) / 4, n2 = (1024 * 1024) / 4;
  for (int i = blockIdx.x * 256 + threadIdx.x; i < n1 + n2; i += gridDim.x * 256) {
    float4 v = (i < n1) ? wqkv[i] : ow[i - n1];
    short4v s;
    s[0] = f2bf(v.x); s[1] = f2bf(v.y); s[2] = f2bf(v.z); s[3] = f2bf(v.w);
    if (i < n1) dq[i] = s; else dow[i - n1] = s;
  }
}

// ---- LayerNorm: one block per row of 1024, bf16 out ------------------------
__global__ __launch_bounds__(256) void k_ln(const float* __restrict__ x,
                                            const float* __restrict__ w,
                                            const float* __restrict__ bb,
                                            short* __restrict__ out) {
  const int row = blockIdx.x, t = threadIdx.x;
  float4 v = ((const float4*)(x + row * 1024))[t];
  float s = v.x + v.y + v.z + v.w;
  float sq = v.x * v.x + v.y * v.y + v.z * v.z + v.w * v.w;
#pragma unroll
  for (int off = 32; off; off >>= 1) { s += __shfl_down(s, off); sq += __shfl_down(sq, off); }
  __shared__ float ls[4], lq[4];
  if ((t & 63) == 0) { ls[t >> 6] = s; lq[t >> 6] = sq; }
  __syncthreads();
  s = ls[0] + ls[1] + ls[2] + ls[3];
  sq = lq[0] + lq[1] + lq[2] + lq[3];
  float mu = s * (1.0f / 1024.0f);
  float var = sq * (1.0f / 1024.0f) - mu * mu;
  float rs = rsqrtf(fmaxf(var, 0.0f) + 1e-12f);
  float4 wv = ((const float4*)w)[t];
  float4 bv = ((const float4*)bb)[t];
  short4v o;
  o[0] = f2bf((v.x - mu) * rs * wv.x + bv.x);
  o[1] = f2bf((v.y - mu) * rs * wv.y + bv.y);
  o[2] = f2bf((v.z - mu) * rs * wv.z + bv.z);
  o[3] = f2bf((v.w - mu) * rs * wv.w + bv.w);
  ((short4v*)out)[row * 256 + t] = o;
}

// ---- bf16 GEMM C[M,N] = A[M,K] @ Bm[N,K]^T, 128x128x32, m97 staging --------
// MODE 0: QKV epilogue. q: bf16 head-layout pre-scaled by 0.125*log2e.
//         k: bf16 head-layout + fp32 out[1]. v: fp32 out[2] ONLY (coalesced;
//         transpose handled by k_vt). MODE 1: plain fp32 store.
template <int MODE>
__global__ __launch_bounds__(256) void k_gemm(const short* __restrict__ A,
                                              const short* __restrict__ Bm,
                                              const float* __restrict__ bias,
                                              float* __restrict__ out,
                                              short* __restrict__ qkvh,
                                              int K, int N) {
  __shared__ short As[128 * 32], Bs[128 * 32];
  const int tid = threadIdx.x, lane = tid & 63, w = tid >> 6;
  const int quad = lane >> 4, l15 = lane & 15;
  const int wr = w >> 1, wc = w & 1;
  const int m0 = blockIdx.y * 128, n0 = blockIdx.x * 128;
  floatx4 acc[4][4] = {};
  for (int k0 = 0; k0 < K; k0 += 32) {
    __syncthreads();
#pragma unroll
    for (int r = 0; r < 2; r++) {
      int pb = r * 256 + w * 64;
      int p = pb + lane;
      int row = p >> 2, c = (p & 3) ^ ((p >> 3) & 3);
      async16(&A[(m0 + row) * K + k0 + c * 8], &As[pb * 8]);
      async16(&Bm[(n0 + row) * K + k0 + c * 8], &Bs[pb * 8]);
    }
    __syncthreads();
    short8 af[4], bf[4];
#pragma unroll
    for (int i = 0; i < 4; i++) {
      int ar = wr * 64 + i * 16 + l15;
      af[i] = *(const short8*)&As[ar * 32 + ((quad ^ ((ar >> 1) & 3)) * 8)];
      int br = wc * 64 + i * 16 + l15;
      bf[i] = *(const short8*)&Bs[br * 32 + ((quad ^ ((br >> 1) & 3)) * 8)];
    }
#pragma unroll
    for (int i = 0; i < 4; i++)
#pragma unroll
      for (int j = 0; j < 4; j++)
        acc[i][j] = __builtin_amdgcn_mfma_f32_16x16x32_bf16(af[i], bf[j], acc[i][j], 0, 0, 0);
  }
  const int grB = m0 + wr * 64, gcB = n0 + wc * 64;
  const float QS = 0.125f * LOG2E;
#pragma unroll
  for (int i = 0; i < 4; i++) {
#pragma unroll
    for (int j = 0; j < 4; j++) {
      int gc = gcB + j * 16 + l15;
      if (MODE == 0) {
        float bv = bias[gc];
        int part = gc >> 10, within = gc & 1023;
        int head = within >> 6, dd = within & 63;
#pragma unroll
        for (int reg = 0; reg < 4; reg++) {
          int gr = grB + i * 16 + quad * 4 + reg;
          float val = acc[i][j][reg] + bv;
          int b_ = gr >> 11, s_ = gr & 2047;
          int hs = (b_ * 16 + head);
          if (part == 0) {
            qkvh[(hs * 2048 + s_) * 64 + dd] = f2bf(val * QS);
          } else if (part == 1) {
            qkvh[PART_STRIDE + (hs * 2048 + s_) * 64 + dd] = f2bf(val);
            out[BSH + gr * 1024 + within] = val;
          } else {
            out[2 * BSH + gr * 1024 + within] = val;
          }
        }
      } else {
#pragma unroll
        for (int reg = 0; reg < 4; reg++) {
          int gr = grB + i * 16 + quad * 4 + reg;
          out[gr * N + gc] = acc[i][j][reg];
        }
      }
    }
  }
}

// ---- V transpose: fp32 [b][s][h*64+d] -> bf16 [b*16+h][d][s] ---------------
// One block per (64-s-tile, h, b). L2-warm reads (just written by k_gemm<0>).
__global__ __launch_bounds__(256) void k_vt(const float* __restrict__ vsrc,
                                            short* __restrict__ vt) {
  const int st = blockIdx.x, h = blockIdx.y, b = blockIdx.z;
  const int t = threadIdx.x;
  __shared__ short Ls[64 * 64];
  const int s0 = st * 64;
#pragma unroll
  for (int j = 0; j < 4; j++) {
    int flat = j * 1024 + t * 4;
    int sl = flat >> 6, d = flat & 63;
    float4 v4 = *(const float4*)&vsrc[(size_t)(b * 2048 + s0 + sl) * 1024 + h * 64 + d];
    short4v s4;
    s4[0] = f2bf(v4.x); s4[1] = f2bf(v4.y); s4[2] = f2bf(v4.z); s4[3] = f2bf(v4.w);
    *(short4v*)&Ls[sl * 64 + (((d >> 3) ^ (sl & 7)) * 8) + (d & 7)] = s4;
  }
  __syncthreads();
  const int d = t >> 2, sbase = (t & 3) * 16;
#pragma unroll
  for (int half = 0; half < 2; half++) {
    short8 o;
#pragma unroll
    for (int j = 0; j < 8; j++) {
      int s = sbase + half * 8 + j;
      o[j] = Ls[s * 64 + (((d >> 3) ^ (s & 7)) * 8) + (d & 7)];
    }
    *(short8*)&vt[(size_t)((b * 16 + h) * 64 + d) * 2048 + s0 + sbase + half * 8] = o;
  }
}

// ---- flash attention R4: block = (qt, h, b), 128 q-rows, BK=64 -------------
// Each wave owns 32 q-rows as 2x16 tiles; K/V fragment reads shared across
// both tiles. Swapped QK^T: sc = mfma(K, Q) => C rows = k, cols = q, so each
// lane holds 4 k-consecutive scores -> packed ds_write_b64 into the wave-
// private P band (logical layout P[q][k] at q*64 + ((k>>3 ^ (q&7))*8)+(k&7),
// same XOR swizzle family as before; write is exactly bank-uniform).
// No online max (scores bounded; exp2 domain). Row sums via ones-MFMA.
__global__ __launch_bounds__(256, 3) void k_attn(const short* __restrict__ qkvh,
                                                 const float* __restrict__ mask,
                                                 float* __restrict__ ctx_out,
                                                 short* __restrict__ ctx_bf) {
  const int qt = blockIdx.x, h = blockIdx.y, b = blockIdx.z;
  const int tid = threadIdx.x, lane = tid & 63, w = tid >> 6;
  const int quad = lane >> 4, l15 = lane & 15;
  __shared__ short Ks[2][64 * 64];
  __shared__ short Vt[2][64 * 64];
  __shared__ short Pl[4][32 * 64];  // per-wave band: 32 q-rows x 64 k
  const short* qg = qkvh + (size_t)(b * 16 + h) * 2048 * 64;
  const short* kg = qg + PART_STRIDE;
  const short* vg = qkvh + 2 * PART_STRIDE + (size_t)(b * 16 + h) * 64 * 2048;  // [d][s]
  const float* mb = mask + b * 2048;

  // Q fragments: 2 row-tiles x 2 d-halves (B-operand of the swapped MFMA)
  short8 qf[2][2];
#pragma unroll
  for (int rt = 0; rt < 2; rt++) {
    const int qr = qt * 128 + w * 32 + rt * 16 + l15;
#pragma unroll
    for (int ks = 0; ks < 2; ks++)
      qf[rt][ks] = *(const short8*)&qg[qr * 64 + ks * 32 + quad * 8];
  }

  short8 ones;
#pragma unroll
  for (int j = 0; j < 8; j++) ones[j] = (short)0x3F80;  // bf16 1.0

  floatx4 accO[2][4] = {};
  floatx4 accL[2] = {};

  auto stage = [&](int kt, int bi) {
#pragma unroll
    for (int r = 0; r < 2; r++) {
      int pb = r * 256 + w * 64;
      int p = pb + lane;
      int row = p >> 3, c = (p & 7) ^ (row & 7);
      async16(&kg[(kt * 64 + row) * 64 + c * 8], &Ks[bi][pb * 8]);
      async16(&vg[row * 2048 + kt * 64 + c * 8], &Vt[bi][pb * 8]);
    }
  };
  stage(0, 0);

  for (int kt = 0; kt < 32; kt++) {
    const int cur = kt & 1;
    __syncthreads();                     // buf[cur] resident; buf[cur^1] free
    if (kt + 1 < 32) stage(kt + 1, cur ^ 1);

    // mask: k is on the reg axis now -> vector float4 loads
    float mv[4][4];
#pragma unroll
    for (int nt = 0; nt < 4; nt++) {
      float4 t = *(const float4*)&mb[kt * 64 + nt * 16 + quad * 4];
      mv[nt][0] = t.x; mv[nt][1] = t.y; mv[nt][2] = t.z; mv[nt][3] = t.w;
    }

    // S^T = K Q^T  (16 MFMA, 8 kf reads shared across both row-tiles)
    floatx4 sc[2][4] = {};
#pragma unroll
    for (int nt = 0; nt < 4; nt++) {
      const int krow = nt * 16 + l15;
#pragma unroll
      for (int ks = 0; ks < 2; ks++) {
        short8 kf = *(const short8*)&Ks[cur][krow * 64 + (((ks * 4 + quad) ^ (krow & 7)) * 8)];
        sc[0][nt] = __builtin_amdgcn_mfma_f32_16x16x32_bf16(kf, qf[0][ks], sc[0][nt], 0, 0, 0);
        sc[1][nt] = __builtin_amdgcn_mfma_f32_16x16x32_bf16(kf, qf[1][ks], sc[1][nt], 0, 0, 0);
      }
    }

    // p = exp2(s + m*log2e); 4 k-consecutive scores pack -> one b64 write.
    // k = nt*16 + quad*4 + reg  =>  k>>3 = nt*2 + (quad>>1), k&7 = (quad&1)*4+reg
#pragma unroll
    for (int rt = 0; rt < 2; rt++) {
      const int qb = rt * 16 + l15;
      const int base = qb * 64 + (quad & 1) * 4;
      const int sw = qb & 7;
#pragma unroll
      for (int nt = 0; nt < 4; nt++) {
        const int v = nt * 2 + (quad >> 1);
        short4v p4;
#pragma unroll
        for (int reg = 0; reg < 4; reg++)
          p4[reg] = f2bf_fast(__builtin_amdgcn_exp2f(
              fmaf(mv[nt][reg], LOG2E, sc[rt][nt][reg])));
        *(short4v*)&Pl[w][base + ((v ^ sw) * 8)] = p4;
      }
    }

    // O += P V ; L += P 1  (20 MFMA, 8 vf reads shared across row-tiles)
#pragma unroll
    for (int ks2 = 0; ks2 < 2; ks2++) {
      short8 pf[2];
#pragma unroll
      for (int rt = 0; rt < 2; rt++) {
        const int prow = rt * 16 + l15;
        pf[rt] = *(const short8*)&Pl[w][prow * 64 + (((ks2 * 4 + quad) ^ (prow & 7)) * 8)];
        accL[rt] = __builtin_amdgcn_mfma_f32_16x16x32_bf16(pf[rt], ones, accL[rt], 0, 0, 0);
      }
#pragma unroll
      for (int nt2 = 0; nt2 < 4; nt2++) {
        const int vrow = nt2 * 16 + l15;
        short8 vf = *(const short8*)&Vt[cur][vrow * 64 + (((ks2 * 4 + quad) ^ (vrow & 7)) * 8)];
        accO[0][nt2] = __builtin_amdgcn_mfma_f32_16x16x32_bf16(pf[0], vf, accO[0][nt2], 0, 0, 0);
        accO[1][nt2] = __builtin_amdgcn_mfma_f32_16x16x32_bf16(pf[1], vf, accO[1][nt2], 0, 0, 0);
      }
    }
  }

  // epilogue: divide by row sums; fp32 -> d_out slice 3, bf16 -> ws
#pragma unroll
  for (int rt = 0; rt < 2; rt++) {
    float inv[4];
#pragma unroll
    for (int reg = 0; reg < 4; reg++) inv[reg] = 1.0f / accL[rt][reg];
#pragma unroll
    for (int nt2 = 0; nt2 < 4; nt2++)
#pragma unroll
      for (int reg = 0; reg < 4; reg++) {
        const int qrow = qt * 128 + w * 32 + rt * 16 + quad * 4 + reg;
        const int col = h * 64 + nt2 * 16 + l15;
        const int gi = (b * 2048 + qrow) * 1024 + col;
        float val = accO[rt][nt2][reg] * inv[reg];
        ctx_out[gi] = val;
        ctx_bf[gi] = f2bf(val);
      }
  }
}

// ---------------------------------------------------------------------------
extern "C" void kernel_launch(void* const* d_in, const int* in_sizes, int n_in,
                              void* d_out, int out_size, void* d_ws, size_t ws_size,
                              hipStream_t stream) {
  const float* x    = (const float*)d_in[0];
  const float* mask = (const float*)d_in[1];
  const float* nw   = (const float*)d_in[2];
  const float* nb   = (const float*)d_in[3];
  const float* wqkv = (const float*)d_in[4];
  const float* bqkv = (const float*)d_in[5];
  const float* ow   = (const float*)d_in[6];
  float* out = (float*)d_out;
  char* ws = (char*)d_ws;

  // ws layout (bytes): [0,16M) ln_bf16 (aliased later as ctx_bf16);
  // [16M,22.3M) wqkv bf16; [22.3M,24M) ow bf16;
  // [24M,+16M) q head-layout; [+16M,+32M) k head-layout; [+32M,+48M) v^T
  short* lnb   = (short*)ws;
  short* wqkvb = (short*)(ws + 16777216);
  short* owb   = (short*)(ws + 23068672);
  short* qkvh  = (short*)(ws + 25165824);
  short* vt    = qkvh + 2 * (size_t)PART_STRIDE;

  k_convert<<<512, 256, 0, stream>>>((const float4*)wqkv, (const float4*)ow,
                                     (short4v*)wqkvb, (short4v*)owb);
  k_ln<<<8192, 256, 0, stream>>>(x, nw, nb, lnb);
  k_gemm<0><<<dim3(24, 64), 256, 0, stream>>>(lnb, wqkvb, bqkv, out, qkvh, 1024, 3072);
  k_vt<<<dim3(32, 16, 4), 256, 0, stream>>>(out + 2 * (size_t)BSH, vt);
  k_attn<<<dim3(16, 16, 4), 256, 0, stream>>>(qkvh, mask, out + 3 * (size_t)BSH, lnb);
  k_gemm<1><<<dim3(8, 64), 256, 0, stream>>>(lnb, owb, nullptr, out, nullptr, 1024, 1024);
}

// Round 2
// 385.513 us; speedup vs baseline: 1.0853x; 1.0527x over previous
//
#include <hip/hip_runtime.h>
#include <cstdint>

// ---------------------------------------------------------------------------
// DeepSpeedSelfAttention fused: LN -> QKV GEMM -> flash attention -> out proj
// B=4 S=2048 H=1024 HEADS=16 DHEAD=64. bf16 MFMA 16x16x32 everywhere.
// R5: k_attn R4 was latency-bound (nothing saturated: LDS ~50%, MFMA 26%,
// VALU 39%, occ 24%). This round removes the P LDS round-trip entirely:
// after swapped QK^T each lane already holds P[q=l15][k], q lane-local; the
// k-octets are routed to the right quads IN REGISTERS via
// v_cvt_pk_bf16_f32 + v_permlane32_swap_b32 + v_permlane16_swap_b32
// (16 cvt_pk + 16 swaps per wave-kt, pure VALU). Kills the 4.19M bank-
// conflict cycles, the ds_write/ds_read latency chain, and frees 16 KB LDS
// -> 32 KB -> 4 blocks/CU (launch_bounds(256,4), VGPR<=128).
// Outputs: [0] out_proj [1] key [2] value [3] context (f32 each).
// ---------------------------------------------------------------------------

typedef __attribute__((ext_vector_type(8))) short short8;
typedef __attribute__((ext_vector_type(4))) short short4v;
typedef __attribute__((ext_vector_type(4))) float floatx4;

#define BSH 8388608
#define PART_STRIDE 8388608
#define LOG2E 1.4426950408889634f

static __device__ __forceinline__ short f2bf(float f) {  // RNE
  union { float f; uint32_t u; } v; v.f = f;
  uint32_t r = v.u + 0x7fffu + ((v.u >> 16) & 1u);
  return (short)(r >> 16);
}

// async global->LDS, width 16. LDS dest = wave-uniform base + lane*16.
typedef __attribute__((address_space(1))) void gas_t;
typedef __attribute__((address_space(3))) void las_t;
static __device__ __forceinline__ void async16(const void* g, const void* l) {
  __builtin_amdgcn_global_load_lds((gas_t*)(uintptr_t)g,
                                   (las_t*)(uint32_t)(uintptr_t)l, 16, 0, 0);
}

// pack 2 f32 -> 1 dword of 2 bf16 (lo = a, hi = b)
static __device__ __forceinline__ uint32_t cvt_pk_bf16(float a, float b) {
  uint32_t r;
  asm("v_cvt_pk_bf16_f32 %0, %1, %2" : "=v"(r) : "v"(a), "v"(b));
  return r;
}
// vdst lanes[32:63] <-> vsrc lanes[0:31]
static __device__ __forceinline__ void swap32(uint32_t& a, uint32_t& b) {
  asm("v_permlane32_swap_b32 %0, %1" : "+v"(a), "+v"(b));
}
// vdst odd 16-rows <-> vsrc even 16-rows (16-31<->0-15, 48-63<->32-47)
static __device__ __forceinline__ void swap16(uint32_t& a, uint32_t& b) {
  asm("v_permlane16_swap_b32 %0, %1" : "+v"(a), "+v"(b));
}
static __device__ __forceinline__ short8 s8_from(uint32_t a, uint32_t b,
                                                 uint32_t c, uint32_t d) {
  union { uint32_t u[4]; short8 s; } t;
  t.u[0] = a; t.u[1] = b; t.u[2] = c; t.u[3] = d;
  return t.s;
}

// ---- fp32 -> bf16 weight conversion ---------------------------------------
__global__ __launch_bounds__(256) void k_convert(const float4* __restrict__ wqkv,
                                                 const float4* __restrict__ ow,
                                                 short4v* __restrict__ dq,
                                                 short4v* __restrict__ dow) {
  const int n1 = (3072 * 1024) / 4, n2 = (1024 * 1024) / 4;
  for (int i = blockIdx.x * 256 + threadIdx.x; i < n1 + n2; i += gridDim.x * 256) {
    float4 v = (i < n1) ? wqkv[i] : ow[i - n1];
    short4v s;
    s[0] = f2bf(v.x); s[1] = f2bf(v.y); s[2] = f2bf(v.z); s[3] = f2bf(v.w);
    if (i < n1) dq[i] = s; else dow[i - n1] = s;
  }
}

// ---- LayerNorm: one block per row of 1024, bf16 out ------------------------
__global__ __launch_bounds__(256) void k_ln(const float* __restrict__ x,
                                            const float* __restrict__ w,
                                            const float* __restrict__ bb,
                                            short* __restrict__ out) {
  const int row = blockIdx.x, t = threadIdx.x;
  float4 v = ((const float4*)(x + row * 1024))[t];
  float s = v.x + v.y + v.z + v.w;
  float sq = v.x * v.x + v.y * v.y + v.z * v.z + v.w * v.w;
#pragma unroll
  for (int off = 32; off; off >>= 1) { s += __shfl_down(s, off); sq += __shfl_down(sq, off); }
  __shared__ float ls[4], lq[4];
  if ((t & 63) == 0) { ls[t >> 6] = s; lq[t >> 6] = sq; }
  __syncthreads();
  s = ls[0] + ls[1] + ls[2] + ls[3];
  sq = lq[0] + lq[1] + lq[2] + lq[3];
  float mu = s * (1.0f / 1024.0f);
  float var = sq * (1.0f / 1024.0f) - mu * mu;
  float rs = rsqrtf(fmaxf(var, 0.0f) + 1e-12f);
  float4 wv = ((const float4*)w)[t];
  float4 bv = ((const float4*)bb)[t];
  short4v o;
  o[0] = f2bf((v.x - mu) * rs * wv.x + bv.x);
  o[1] = f2bf((v.y - mu) * rs * wv.y + bv.y);
  o[2] = f2bf((v.z - mu) * rs * wv.z + bv.z);
  o[3] = f2bf((v.w - mu) * rs * wv.w + bv.w);
  ((short4v*)out)[row * 256 + t] = o;
}

// ---- bf16 GEMM C[M,N] = A[M,K] @ Bm[N,K]^T, 128x128x32, m97 staging --------
// MODE 0: QKV epilogue. q: bf16 head-layout pre-scaled by 0.125*log2e.
//         k: bf16 head-layout + fp32 out[1]. v: fp32 out[2] ONLY (coalesced;
//         transpose handled by k_vt). MODE 1: plain fp32 store.
template <int MODE>
__global__ __launch_bounds__(256) void k_gemm(const short* __restrict__ A,
                                              const short* __restrict__ Bm,
                                              const float* __restrict__ bias,
                                              float* __restrict__ out,
                                              short* __restrict__ qkvh,
                                              int K, int N) {
  __shared__ short As[128 * 32], Bs[128 * 32];
  const int tid = threadIdx.x, lane = tid & 63, w = tid >> 6;
  const int quad = lane >> 4, l15 = lane & 15;
  const int wr = w >> 1, wc = w & 1;
  const int m0 = blockIdx.y * 128, n0 = blockIdx.x * 128;
  floatx4 acc[4][4] = {};
  for (int k0 = 0; k0 < K; k0 += 32) {
    __syncthreads();
#pragma unroll
    for (int r = 0; r < 2; r++) {
      int pb = r * 256 + w * 64;
      int p = pb + lane;
      int row = p >> 2, c = (p & 3) ^ ((p >> 3) & 3);
      async16(&A[(m0 + row) * K + k0 + c * 8], &As[pb * 8]);
      async16(&Bm[(n0 + row) * K + k0 + c * 8], &Bs[pb * 8]);
    }
    __syncthreads();
    short8 af[4], bf[4];
#pragma unroll
    for (int i = 0; i < 4; i++) {
      int ar = wr * 64 + i * 16 + l15;
      af[i] = *(const short8*)&As[ar * 32 + ((quad ^ ((ar >> 1) & 3)) * 8)];
      int br = wc * 64 + i * 16 + l15;
      bf[i] = *(const short8*)&Bs[br * 32 + ((quad ^ ((br >> 1) & 3)) * 8)];
    }
#pragma unroll
    for (int i = 0; i < 4; i++)
#pragma unroll
      for (int j = 0; j < 4; j++)
        acc[i][j] = __builtin_amdgcn_mfma_f32_16x16x32_bf16(af[i], bf[j], acc[i][j], 0, 0, 0);
  }
  const int grB = m0 + wr * 64, gcB = n0 + wc * 64;
  const float QS = 0.125f * LOG2E;
#pragma unroll
  for (int i = 0; i < 4; i++) {
#pragma unroll
    for (int j = 0; j < 4; j++) {
      int gc = gcB + j * 16 + l15;
      if (MODE == 0) {
        float bv = bias[gc];
        int part = gc >> 10, within = gc & 1023;
        int head = within >> 6, dd = within & 63;
#pragma unroll
        for (int reg = 0; reg < 4; reg++) {
          int gr = grB + i * 16 + quad * 4 + reg;
          float val = acc[i][j][reg] + bv;
          int b_ = gr >> 11, s_ = gr & 2047;
          int hs = (b_ * 16 + head);
          if (part == 0) {
            qkvh[(hs * 2048 + s_) * 64 + dd] = f2bf(val * QS);
          } else if (part == 1) {
            qkvh[PART_STRIDE + (hs * 2048 + s_) * 64 + dd] = f2bf(val);
            out[BSH + gr * 1024 + within] = val;
          } else {
            out[2 * BSH + gr * 1024 + within] = val;
          }
        }
      } else {
#pragma unroll
        for (int reg = 0; reg < 4; reg++) {
          int gr = grB + i * 16 + quad * 4 + reg;
          out[gr * N + gc] = acc[i][j][reg];
        }
      }
    }
  }
}

// ---- V transpose: fp32 [b][s][h*64+d] -> bf16 [b*16+h][d][s] ---------------
// One block per (64-s-tile, h, b). L2-warm reads (just written by k_gemm<0>).
__global__ __launch_bounds__(256) void k_vt(const float* __restrict__ vsrc,
                                            short* __restrict__ vt) {
  const int st = blockIdx.x, h = blockIdx.y, b = blockIdx.z;
  const int t = threadIdx.x;
  __shared__ short Ls[64 * 64];
  const int s0 = st * 64;
#pragma unroll
  for (int j = 0; j < 4; j++) {
    int flat = j * 1024 + t * 4;
    int sl = flat >> 6, d = flat & 63;
    float4 v4 = *(const float4*)&vsrc[(size_t)(b * 2048 + s0 + sl) * 1024 + h * 64 + d];
    short4v s4;
    s4[0] = f2bf(v4.x); s4[1] = f2bf(v4.y); s4[2] = f2bf(v4.z); s4[3] = f2bf(v4.w);
    *(short4v*)&Ls[sl * 64 + (((d >> 3) ^ (sl & 7)) * 8) + (d & 7)] = s4;
  }
  __syncthreads();
  const int d = t >> 2, sbase = (t & 3) * 16;
#pragma unroll
  for (int half = 0; half < 2; half++) {
    short8 o;
#pragma unroll
    for (int j = 0; j < 8; j++) {
      int s = sbase + half * 8 + j;
      o[j] = Ls[s * 64 + (((d >> 3) ^ (s & 7)) * 8) + (d & 7)];
    }
    *(short8*)&vt[(size_t)((b * 16 + h) * 64 + d) * 2048 + s0 + sbase + half * 8] = o;
  }
}

// ---- flash attention R5: block = (qt, h, b), 128 q-rows, BK=64 -------------
// Swapped QK^T: sc = mfma(K, Q) => lane (l15,quad) holds
// P[q=l15][k = nt*16 + quad*4 + reg]. PV A-frag needs lane to hold
// P[q=l15][k = ks2*32 + quad*8 + j] -- q already lane-local, only k-octets
// need routing across quads. Pair X[2e][d]=cvt_pk(p[2e][2d],p[2e][2d+1])
// with X[2e+1][d]; permlane32_swap then permlane16_swap yields
// rE = A-frag dword m=d, rO = m=2+d of chunk ks2=e (lane-table verified).
// No LDS for P at all. No online max (scores bounded; exp2 domain).
// Row sums via ones-MFMA. LDS 32 KiB -> 4 blocks/CU.
__global__ __launch_bounds__(256, 4) void k_attn(const short* __restrict__ qkvh,
                                                 const float* __restrict__ mask,
                                                 float* __restrict__ ctx_out,
                                                 short* __restrict__ ctx_bf) {
  const int qt = blockIdx.x, h = blockIdx.y, b = blockIdx.z;
  const int tid = threadIdx.x, lane = tid & 63, w = tid >> 6;
  const int quad = lane >> 4, l15 = lane & 15;
  __shared__ short Ks[2][64 * 64];
  __shared__ short Vt[2][64 * 64];
  const short* qg = qkvh + (size_t)(b * 16 + h) * 2048 * 64;
  const short* kg = qg + PART_STRIDE;
  const short* vg = qkvh + 2 * PART_STRIDE + (size_t)(b * 16 + h) * 64 * 2048;  // [d][s]
  const float* mb = mask + b * 2048;

  // Q fragments: 2 row-tiles x 2 d-halves (B-operand of the swapped MFMA)
  short8 qf[2][2];
#pragma unroll
  for (int rt = 0; rt < 2; rt++) {
    const int qr = qt * 128 + w * 32 + rt * 16 + l15;
#pragma unroll
    for (int ks = 0; ks < 2; ks++)
      qf[rt][ks] = *(const short8*)&qg[qr * 64 + ks * 32 + quad * 8];
  }

  short8 ones;
#pragma unroll
  for (int j = 0; j < 8; j++) ones[j] = (short)0x3F80;  // bf16 1.0

  floatx4 accO[2][4] = {};
  floatx4 accL[2] = {};

  auto stage = [&](int kt, int bi) {
#pragma unroll
    for (int r = 0; r < 2; r++) {
      int pb = r * 256 + w * 64;
      int p = pb + lane;
      int row = p >> 3, c = (p & 7) ^ (row & 7);
      async16(&kg[(kt * 64 + row) * 64 + c * 8], &Ks[bi][pb * 8]);
      async16(&vg[row * 2048 + kt * 64 + c * 8], &Vt[bi][pb * 8]);
    }
  };
  stage(0, 0);

  for (int kt = 0; kt < 32; kt++) {
    const int cur = kt & 1;
    __syncthreads();                     // buf[cur] resident; buf[cur^1] free
    if (kt + 1 < 32) stage(kt + 1, cur ^ 1);

    // mask: k on the reg axis -> vector float4 loads
    float mv[4][4];
#pragma unroll
    for (int nt = 0; nt < 4; nt++) {
      float4 t = *(const float4*)&mb[kt * 64 + nt * 16 + quad * 4];
      mv[nt][0] = t.x; mv[nt][1] = t.y; mv[nt][2] = t.z; mv[nt][3] = t.w;
    }

    // S^T = K Q^T  (16 MFMA, 8 kf reads shared across both row-tiles)
    floatx4 sc[2][4] = {};
#pragma unroll
    for (int nt = 0; nt < 4; nt++) {
      const int krow = nt * 16 + l15;
#pragma unroll
      for (int ks = 0; ks < 2; ks++) {
        short8 kf = *(const short8*)&Ks[cur][krow * 64 + (((ks * 4 + quad) ^ (krow & 7)) * 8)];
        sc[0][nt] = __builtin_amdgcn_mfma_f32_16x16x32_bf16(kf, qf[0][ks], sc[0][nt], 0, 0, 0);
        sc[1][nt] = __builtin_amdgcn_mfma_f32_16x16x32_bf16(kf, qf[1][ks], sc[1][nt], 0, 0, 0);
      }
    }

    // p = exp2(s + m*log2e) -> bf16 pack -> cross-quad routing in registers.
    // pa[rt][ks2][m]: A-frag dwords for PV.
    uint32_t pa[2][2][4];
#pragma unroll
    for (int rt = 0; rt < 2; rt++) {
#pragma unroll
      for (int e = 0; e < 2; e++) {
#pragma unroll
        for (int d = 0; d < 2; d++) {
          float p0 = __builtin_amdgcn_exp2f(fmaf(mv[2 * e][2 * d], LOG2E, sc[rt][2 * e][2 * d]));
          float p1 = __builtin_amdgcn_exp2f(fmaf(mv[2 * e][2 * d + 1], LOG2E, sc[rt][2 * e][2 * d + 1]));
          float p2 = __builtin_amdgcn_exp2f(fmaf(mv[2 * e + 1][2 * d], LOG2E, sc[rt][2 * e + 1][2 * d]));
          float p3 = __builtin_amdgcn_exp2f(fmaf(mv[2 * e + 1][2 * d + 1], LOG2E, sc[rt][2 * e + 1][2 * d + 1]));
          uint32_t rE = cvt_pk_bf16(p0, p1);  // X[2e][d]
          uint32_t rO = cvt_pk_bf16(p2, p3);  // X[2e+1][d]
          swap32(rE, rO);
          swap16(rE, rO);
          pa[rt][e][d] = rE;      // A[ks2=e][m=d]
          pa[rt][e][2 + d] = rO;  // A[ks2=e][m=2+d]
        }
      }
    }

    // O += P V ; L += P 1  (20 MFMA, 8 vf reads shared across row-tiles)
#pragma unroll
    for (int ks2 = 0; ks2 < 2; ks2++) {
      short8 pf0 = s8_from(pa[0][ks2][0], pa[0][ks2][1], pa[0][ks2][2], pa[0][ks2][3]);
      short8 pf1 = s8_from(pa[1][ks2][0], pa[1][ks2][1], pa[1][ks2][2], pa[1][ks2][3]);
      accL[0] = __builtin_amdgcn_mfma_f32_16x16x32_bf16(pf0, ones, accL[0], 0, 0, 0);
      accL[1] = __builtin_amdgcn_mfma_f32_16x16x32_bf16(pf1, ones, accL[1], 0, 0, 0);
#pragma unroll
      for (int nt2 = 0; nt2 < 4; nt2++) {
        const int vrow = nt2 * 16 + l15;
        short8 vf = *(const short8*)&Vt[cur][vrow * 64 + (((ks2 * 4 + quad) ^ (vrow & 7)) * 8)];
        accO[0][nt2] = __builtin_amdgcn_mfma_f32_16x16x32_bf16(pf0, vf, accO[0][nt2], 0, 0, 0);
        accO[1][nt2] = __builtin_amdgcn_mfma_f32_16x16x32_bf16(pf1, vf, accO[1][nt2], 0, 0, 0);
      }
    }
  }

  // epilogue: divide by row sums; fp32 -> d_out slice 3, bf16 -> ws
#pragma unroll
  for (int rt = 0; rt < 2; rt++) {
    float inv[4];
#pragma unroll
    for (int reg = 0; reg < 4; reg++) inv[reg] = 1.0f / accL[rt][reg];
#pragma unroll
    for (int nt2 = 0; nt2 < 4; nt2++)
#pragma unroll
      for (int reg = 0; reg < 4; reg++) {
        const int qrow = qt * 128 + w * 32 + rt * 16 + quad * 4 + reg;
        const int col = h * 64 + nt2 * 16 + l15;
        const int gi = (b * 2048 + qrow) * 1024 + col;
        float val = accO[rt][nt2][reg] * inv[reg];
        ctx_out[gi] = val;
        ctx_bf[gi] = f2bf(val);
      }
  }
}

// ---------------------------------------------------------------------------
extern "C" void kernel_launch(void* const* d_in, const int* in_sizes, int n_in,
                              void* d_out, int out_size, void* d_ws, size_t ws_size,
                              hipStream_t stream) {
  const float* x    = (const float*)d_in[0];
  const float* mask = (const float*)d_in[1];
  const float* nw   = (const float*)d_in[2];
  const float* nb   = (const float*)d_in[3];
  const float* wqkv = (const float*)d_in[4];
  const float* bqkv = (const float*)d_in[5];
  const float* ow   = (const float*)d_in[6];
  float* out = (float*)d_out;
  char* ws = (char*)d_ws;

  // ws layout (bytes): [0,16M) ln_bf16 (aliased later as ctx_bf16);
  // [16M,22.3M) wqkv bf16; [22.3M,24M) ow bf16;
  // [24M,+16M) q head-layout; [+16M,+32M) k head-layout; [+32M,+48M) v^T
  short* lnb   = (short*)ws;
  short* wqkvb = (short*)(ws + 16777216);
  short* owb   = (short*)(ws + 23068672);
  short* qkvh  = (short*)(ws + 25165824);
  short* vt    = qkvh + 2 * (size_t)PART_STRIDE;

  k_convert<<<512, 256, 0, stream>>>((const float4*)wqkv, (const float4*)ow,
                                     (short4v*)wqkvb, (short4v*)owb);
  k_ln<<<8192, 256, 0, stream>>>(x, nw, nb, lnb);
  k_gemm<0><<<dim3(24, 64), 256, 0, stream>>>(lnb, wqkvb, bqkv, out, qkvh, 1024, 3072);
  k_vt<<<dim3(32, 16, 4), 256, 0, stream>>>(out + 2 * (size_t)BSH, vt);
  k_attn<<<dim3(16, 16, 4), 256, 0, stream>>>(qkvh, mask, out + 3 * (size_t)BSH, lnb);
  k_gemm<1><<<dim3(8, 64), 256, 0, stream>>>(lnb, owb, nullptr, out, nullptr, 1024, 1024);
}

// Round 5
// 376.785 us; speedup vs baseline: 1.1104x; 1.0232x over previous
//
#include <hip/hip_runtime.h>
#include <cstdint>

// ---------------------------------------------------------------------------
// DeepSpeedSelfAttention fused: LN -> QKV GEMM -> flash attention -> out proj
// B=4 S=2048 H=1024 HEADS=16 DHEAD=64. bf16 MFMA 16x16x32 everywhere.
// R8 = R5 (last verified-good, 94us k_attn) + XCD-aware block swizzle ONLY.
// R6/R7 pipeline REVERTED: failed correctness (ctx absmax 0.243) with an
// unexplained LDS race; do not commit unexplained changes.
// Swizzle rationale: R5 FETCH_SIZE=139.5MB vs ~64MB ideal reads. qt-fastest
// grid round-robins the 16 blocks sharing one head's K/V (512KB) across all
// 8 XCDs -> per-XCD L2 duplicates K/V fetches. All 1024 blocks co-resident
// (4/CU), so remap wid=(bid&7)*128+(bid>>3): each XCD owns 8 complete (h,b)
// pairs x 16 qt-blocks; per-XCD K/V set = 4MB = L2 size. 1024%8==0 ->
// bijective. Block renaming only => bit-identical output to R5.
// Outputs: [0] out_proj [1] key [2] value [3] context (f32 each).
// ---------------------------------------------------------------------------

typedef __attribute__((ext_vector_type(8))) short short8;
typedef __attribute__((ext_vector_type(4))) short short4v;
typedef __attribute__((ext_vector_type(4))) float floatx4;

#define BSH 8388608
#define PART_STRIDE 8388608
#define LOG2E 1.4426950408889634f

static __device__ __forceinline__ short f2bf(float f) {  // RNE
  union { float f; uint32_t u; } v; v.f = f;
  uint32_t r = v.u + 0x7fffu + ((v.u >> 16) & 1u);
  return (short)(r >> 16);
}

// async global->LDS, width 16. LDS dest = wave-uniform base + lane*16.
typedef __attribute__((address_space(1))) void gas_t;
typedef __attribute__((address_space(3))) void las_t;
static __device__ __forceinline__ void async16(const void* g, const void* l) {
  __builtin_amdgcn_global_load_lds((gas_t*)(uintptr_t)g,
                                   (las_t*)(uint32_t)(uintptr_t)l, 16, 0, 0);
}

// pack 2 f32 -> 1 dword of 2 bf16 (lo = a, hi = b)
static __device__ __forceinline__ uint32_t cvt_pk_bf16(float a, float b) {
  uint32_t r;
  asm("v_cvt_pk_bf16_f32 %0, %1, %2" : "=v"(r) : "v"(a), "v"(b));
  return r;
}
// vdst lanes[32:63] <-> vsrc lanes[0:31]
static __device__ __forceinline__ void swap32(uint32_t& a, uint32_t& b) {
  asm("v_permlane32_swap_b32 %0, %1" : "+v"(a), "+v"(b));
}
// vdst odd 16-rows <-> vsrc even 16-rows (16-31<->0-15, 48-63<->32-47)
static __device__ __forceinline__ void swap16(uint32_t& a, uint32_t& b) {
  asm("v_permlane16_swap_b32 %0, %1" : "+v"(a), "+v"(b));
}
static __device__ __forceinline__ short8 s8_from(uint32_t a, uint32_t b,
                                                 uint32_t c, uint32_t d) {
  union { uint32_t u[4]; short8 s; } t;
  t.u[0] = a; t.u[1] = b; t.u[2] = c; t.u[3] = d;
  return t.s;
}

// ---- fp32 -> bf16 weight conversion ---------------------------------------
__global__ __launch_bounds__(256) void k_convert(const float4* __restrict__ wqkv,
                                                 const float4* __restrict__ ow,
                                                 short4v* __restrict__ dq,
                                                 short4v* __restrict__ dow) {
  const int n1 = (3072 * 1024) / 4, n2 = (1024 * 1024) / 4;
  for (int i = blockIdx.x * 256 + threadIdx.x; i < n1 + n2; i += gridDim.x * 256) {
    float4 v = (i < n1) ? wqkv[i] : ow[i - n1];
    short4v s;
    s[0] = f2bf(v.x); s[1] = f2bf(v.y); s[2] = f2bf(v.z); s[3] = f2bf(v.w);
    if (i < n1) dq[i] = s; else dow[i - n1] = s;
  }
}

// ---- LayerNorm: one block per row of 1024, bf16 out ------------------------
__global__ __launch_bounds__(256) void k_ln(const float* __restrict__ x,
                                            const float* __restrict__ w,
                                            const float* __restrict__ bb,
                                            short* __restrict__ out) {
  const int row = blockIdx.x, t = threadIdx.x;
  float4 v = ((const float4*)(x + row * 1024))[t];
  float s = v.x + v.y + v.z + v.w;
  float sq = v.x * v.x + v.y * v.y + v.z * v.z + v.w * v.w;
#pragma unroll
  for (int off = 32; off; off >>= 1) { s += __shfl_down(s, off); sq += __shfl_down(sq, off); }
  __shared__ float ls[4], lq[4];
  if ((t & 63) == 0) { ls[t >> 6] = s; lq[t >> 6] = sq; }
  __syncthreads();
  s = ls[0] + ls[1] + ls[2] + ls[3];
  sq = lq[0] + lq[1] + lq[2] + lq[3];
  float mu = s * (1.0f / 1024.0f);
  float var = sq * (1.0f / 1024.0f) - mu * mu;
  float rs = rsqrtf(fmaxf(var, 0.0f) + 1e-12f);
  float4 wv = ((const float4*)w)[t];
  float4 bv = ((const float4*)bb)[t];
  short4v o;
  o[0] = f2bf((v.x - mu) * rs * wv.x + bv.x);
  o[1] = f2bf((v.y - mu) * rs * wv.y + bv.y);
  o[2] = f2bf((v.z - mu) * rs * wv.z + bv.z);
  o[3] = f2bf((v.w - mu) * rs * wv.w + bv.w);
  ((short4v*)out)[row * 256 + t] = o;
}

// ---- bf16 GEMM C[M,N] = A[M,K] @ Bm[N,K]^T, 128x128x32, m97 staging --------
// MODE 0: QKV epilogue. q: bf16 head-layout pre-scaled by 0.125*log2e.
//         k: bf16 head-layout + fp32 out[1]. v: fp32 out[2] ONLY (coalesced;
//         transpose handled by k_vt). MODE 1: plain fp32 store.
template <int MODE>
__global__ __launch_bounds__(256) void k_gemm(const short* __restrict__ A,
                                              const short* __restrict__ Bm,
                                              const float* __restrict__ bias,
                                              float* __restrict__ out,
                                              short* __restrict__ qkvh,
                                              int K, int N) {
  __shared__ short As[128 * 32], Bs[128 * 32];
  const int tid = threadIdx.x, lane = tid & 63, w = tid >> 6;
  const int quad = lane >> 4, l15 = lane & 15;
  const int wr = w >> 1, wc = w & 1;
  const int m0 = blockIdx.y * 128, n0 = blockIdx.x * 128;
  floatx4 acc[4][4] = {};
  for (int k0 = 0; k0 < K; k0 += 32) {
    __syncthreads();
#pragma unroll
    for (int r = 0; r < 2; r++) {
      int pb = r * 256 + w * 64;
      int p = pb + lane;
      int row = p >> 2, c = (p & 3) ^ ((p >> 3) & 3);
      async16(&A[(m0 + row) * K + k0 + c * 8], &As[pb * 8]);
      async16(&Bm[(n0 + row) * K + k0 + c * 8], &Bs[pb * 8]);
    }
    __syncthreads();
    short8 af[4], bf[4];
#pragma unroll
    for (int i = 0; i < 4; i++) {
      int ar = wr * 64 + i * 16 + l15;
      af[i] = *(const short8*)&As[ar * 32 + ((quad ^ ((ar >> 1) & 3)) * 8)];
      int br = wc * 64 + i * 16 + l15;
      bf[i] = *(const short8*)&Bs[br * 32 + ((quad ^ ((br >> 1) & 3)) * 8)];
    }
#pragma unroll
    for (int i = 0; i < 4; i++)
#pragma unroll
      for (int j = 0; j < 4; j++)
        acc[i][j] = __builtin_amdgcn_mfma_f32_16x16x32_bf16(af[i], bf[j], acc[i][j], 0, 0, 0);
  }
  const int grB = m0 + wr * 64, gcB = n0 + wc * 64;
  const float QS = 0.125f * LOG2E;
#pragma unroll
  for (int i = 0; i < 4; i++) {
#pragma unroll
    for (int j = 0; j < 4; j++) {
      int gc = gcB + j * 16 + l15;
      if (MODE == 0) {
        float bv = bias[gc];
        int part = gc >> 10, within = gc & 1023;
        int head = within >> 6, dd = within & 63;
#pragma unroll
        for (int reg = 0; reg < 4; reg++) {
          int gr = grB + i * 16 + quad * 4 + reg;
          float val = acc[i][j][reg] + bv;
          int b_ = gr >> 11, s_ = gr & 2047;
          int hs = (b_ * 16 + head);
          if (part == 0) {
            qkvh[(hs * 2048 + s_) * 64 + dd] = f2bf(val * QS);
          } else if (part == 1) {
            qkvh[PART_STRIDE + (hs * 2048 + s_) * 64 + dd] = f2bf(val);
            out[BSH + gr * 1024 + within] = val;
          } else {
            out[2 * BSH + gr * 1024 + within] = val;
          }
        }
      } else {
#pragma unroll
        for (int reg = 0; reg < 4; reg++) {
          int gr = grB + i * 16 + quad * 4 + reg;
          out[gr * N + gc] = acc[i][j][reg];
        }
      }
    }
  }
}

// ---- V transpose: fp32 [b][s][h*64+d] -> bf16 [b*16+h][d][s] ---------------
// One block per (64-s-tile, h, b). L2-warm reads (just written by k_gemm<0>).
__global__ __launch_bounds__(256) void k_vt(const float* __restrict__ vsrc,
                                            short* __restrict__ vt) {
  const int st = blockIdx.x, h = blockIdx.y, b = blockIdx.z;
  const int t = threadIdx.x;
  __shared__ short Ls[64 * 64];
  const int s0 = st * 64;
#pragma unroll
  for (int j = 0; j < 4; j++) {
    int flat = j * 1024 + t * 4;
    int sl = flat >> 6, d = flat & 63;
    float4 v4 = *(const float4*)&vsrc[(size_t)(b * 2048 + s0 + sl) * 1024 + h * 64 + d];
    short4v s4;
    s4[0] = f2bf(v4.x); s4[1] = f2bf(v4.y); s4[2] = f2bf(v4.z); s4[3] = f2bf(v4.w);
    *(short4v*)&Ls[sl * 64 + (((d >> 3) ^ (sl & 7)) * 8) + (d & 7)] = s4;
  }
  __syncthreads();
  const int d = t >> 2, sbase = (t & 3) * 16;
#pragma unroll
  for (int half = 0; half < 2; half++) {
    short8 o;
#pragma unroll
    for (int j = 0; j < 8; j++) {
      int s = sbase + half * 8 + j;
      o[j] = Ls[s * 64 + (((d >> 3) ^ (s & 7)) * 8) + (d & 7)];
    }
    *(short8*)&vt[(size_t)((b * 16 + h) * 64 + d) * 2048 + s0 + sbase + half * 8] = o;
  }
}

// ---- flash attention R8: 1D grid 1024, XCD-swizzled; 128 q-rows, BK=64 -----
// wid = (bid&7)*128 + (bid>>3): XCD x (= bid%8 round-robin) owns contiguous
// work [x*128,(x+1)*128) = 8 (h,b) pairs x 16 qt tiles; K/V per XCD = 4MB
// = L2. Compute body identical to R5 (verified): swapped QK^T, in-register
// P routing (cvt_pk + permlane swaps), no online max, ones-MFMA row sums.
__global__ __launch_bounds__(256, 4) void k_attn(const short* __restrict__ qkvh,
                                                 const float* __restrict__ mask,
                                                 float* __restrict__ ctx_out,
                                                 short* __restrict__ ctx_bf) {
  const int bid = blockIdx.x;
  const int wid = (bid & 7) * 128 + (bid >> 3);
  const int qt = wid & 15, h = (wid >> 4) & 15, b = wid >> 8;
  const int tid = threadIdx.x, lane = tid & 63, w = tid >> 6;
  const int quad = lane >> 4, l15 = lane & 15;
  __shared__ short Ks[2][64 * 64];
  __shared__ short Vt[2][64 * 64];
  const short* qg = qkvh + (size_t)(b * 16 + h) * 2048 * 64;
  const short* kg = qg + PART_STRIDE;
  const short* vg = qkvh + 2 * PART_STRIDE + (size_t)(b * 16 + h) * 64 * 2048;  // [d][s]
  const float* mb = mask + b * 2048;

  // Q fragments: 2 row-tiles x 2 d-halves (B-operand of the swapped MFMA)
  short8 qf[2][2];
#pragma unroll
  for (int rt = 0; rt < 2; rt++) {
    const int qr = qt * 128 + w * 32 + rt * 16 + l15;
#pragma unroll
    for (int ks = 0; ks < 2; ks++)
      qf[rt][ks] = *(const short8*)&qg[qr * 64 + ks * 32 + quad * 8];
  }

  short8 ones;
#pragma unroll
  for (int j = 0; j < 8; j++) ones[j] = (short)0x3F80;  // bf16 1.0

  floatx4 accO[2][4] = {};
  floatx4 accL[2] = {};

  auto stage = [&](int kt, int bi) {
#pragma unroll
    for (int r = 0; r < 2; r++) {
      int pb = r * 256 + w * 64;
      int p = pb + lane;
      int row = p >> 3, c = (p & 7) ^ (row & 7);
      async16(&kg[(kt * 64 + row) * 64 + c * 8], &Ks[bi][pb * 8]);
      async16(&vg[row * 2048 + kt * 64 + c * 8], &Vt[bi][pb * 8]);
    }
  };
  stage(0, 0);

  for (int kt = 0; kt < 32; kt++) {
    const int cur = kt & 1;
    __syncthreads();                     // buf[cur] resident; buf[cur^1] free
    if (kt + 1 < 32) stage(kt + 1, cur ^ 1);

    // mask: k on the reg axis -> vector float4 loads
    float mv[4][4];
#pragma unroll
    for (int nt = 0; nt < 4; nt++) {
      float4 t = *(const float4*)&mb[kt * 64 + nt * 16 + quad * 4];
      mv[nt][0] = t.x; mv[nt][1] = t.y; mv[nt][2] = t.z; mv[nt][3] = t.w;
    }

    // S^T = K Q^T  (16 MFMA, 8 kf reads shared across both row-tiles)
    floatx4 sc[2][4] = {};
#pragma unroll
    for (int nt = 0; nt < 4; nt++) {
      const int krow = nt * 16 + l15;
#pragma unroll
      for (int ks = 0; ks < 2; ks++) {
        short8 kf = *(const short8*)&Ks[cur][krow * 64 + (((ks * 4 + quad) ^ (krow & 7)) * 8)];
        sc[0][nt] = __builtin_amdgcn_mfma_f32_16x16x32_bf16(kf, qf[0][ks], sc[0][nt], 0, 0, 0);
        sc[1][nt] = __builtin_amdgcn_mfma_f32_16x16x32_bf16(kf, qf[1][ks], sc[1][nt], 0, 0, 0);
      }
    }

    // p = exp2(s + m*log2e) -> bf16 pack -> cross-quad routing in registers.
    // pa[rt][ks2][m]: A-frag dwords for PV.
    uint32_t pa[2][2][4];
#pragma unroll
    for (int rt = 0; rt < 2; rt++) {
#pragma unroll
      for (int e = 0; e < 2; e++) {
#pragma unroll
        for (int d = 0; d < 2; d++) {
          float p0 = __builtin_amdgcn_exp2f(fmaf(mv[2 * e][2 * d], LOG2E, sc[rt][2 * e][2 * d]));
          float p1 = __builtin_amdgcn_exp2f(fmaf(mv[2 * e][2 * d + 1], LOG2E, sc[rt][2 * e][2 * d + 1]));
          float p2 = __builtin_amdgcn_exp2f(fmaf(mv[2 * e + 1][2 * d], LOG2E, sc[rt][2 * e + 1][2 * d]));
          float p3 = __builtin_amdgcn_exp2f(fmaf(mv[2 * e + 1][2 * d + 1], LOG2E, sc[rt][2 * e + 1][2 * d + 1]));
          uint32_t rE = cvt_pk_bf16(p0, p1);  // X[2e][d]
          uint32_t rO = cvt_pk_bf16(p2, p3);  // X[2e+1][d]
          swap32(rE, rO);
          swap16(rE, rO);
          pa[rt][e][d] = rE;      // A[ks2=e][m=d]
          pa[rt][e][2 + d] = rO;  // A[ks2=e][m=2+d]
        }
      }
    }

    // O += P V ; L += P 1  (20 MFMA, 8 vf reads shared across row-tiles)
#pragma unroll
    for (int ks2 = 0; ks2 < 2; ks2++) {
      short8 pf0 = s8_from(pa[0][ks2][0], pa[0][ks2][1], pa[0][ks2][2], pa[0][ks2][3]);
      short8 pf1 = s8_from(pa[1][ks2][0], pa[1][ks2][1], pa[1][ks2][2], pa[1][ks2][3]);
      accL[0] = __builtin_amdgcn_mfma_f32_16x16x32_bf16(pf0, ones, accL[0], 0, 0, 0);
      accL[1] = __builtin_amdgcn_mfma_f32_16x16x32_bf16(pf1, ones, accL[1], 0, 0, 0);
#pragma unroll
      for (int nt2 = 0; nt2 < 4; nt2++) {
        const int vrow = nt2 * 16 + l15;
        short8 vf = *(const short8*)&Vt[cur][vrow * 64 + (((ks2 * 4 + quad) ^ (vrow & 7)) * 8)];
        accO[0][nt2] = __builtin_amdgcn_mfma_f32_16x16x32_bf16(pf0, vf, accO[0][nt2], 0, 0, 0);
        accO[1][nt2] = __builtin_amdgcn_mfma_f32_16x16x32_bf16(pf1, vf, accO[1][nt2], 0, 0, 0);
      }
    }
  }

  // epilogue: divide by row sums; fp32 -> d_out slice 3, bf16 -> ws
#pragma unroll
  for (int rt = 0; rt < 2; rt++) {
    float inv[4];
#pragma unroll
    for (int reg = 0; reg < 4; reg++) inv[reg] = 1.0f / accL[rt][reg];
#pragma unroll
    for (int nt2 = 0; nt2 < 4; nt2++)
#pragma unroll
      for (int reg = 0; reg < 4; reg++) {
        const int qrow = qt * 128 + w * 32 + rt * 16 + quad * 4 + reg;
        const int col = h * 64 + nt2 * 16 + l15;
        const int gi = (b * 2048 + qrow) * 1024 + col;
        float val = accO[rt][nt2][reg] * inv[reg];
        ctx_out[gi] = val;
        ctx_bf[gi] = f2bf(val);
      }
  }
}

// ---------------------------------------------------------------------------
extern "C" void kernel_launch(void* const* d_in, const int* in_sizes, int n_in,
                              void* d_out, int out_size, void* d_ws, size_t ws_size,
                              hipStream_t stream) {
  const float* x    = (const float*)d_in[0];
  const float* mask = (const float*)d_in[1];
  const float* nw   = (const float*)d_in[2];
  const float* nb   = (const float*)d_in[3];
  const float* wqkv = (const float*)d_in[4];
  const float* bqkv = (const float*)d_in[5];
  const float* ow   = (const float*)d_in[6];
  float* out = (float*)d_out;
  char* ws = (char*)d_ws;

  // ws layout (bytes): [0,16M) ln_bf16 (aliased later as ctx_bf16);
  // [16M,22.3M) wqkv bf16; [22.3M,24M) ow bf16;
  // [24M,+16M) q head-layout; [+16M,+32M) k head-layout; [+32M,+48M) v^T
  short* lnb   = (short*)ws;
  short* wqkvb = (short*)(ws + 16777216);
  short* owb   = (short*)(ws + 23068672);
  short* qkvh  = (short*)(ws + 25165824);
  short* vt    = qkvh + 2 * (size_t)PART_STRIDE;

  k_convert<<<512, 256, 0, stream>>>((const float4*)wqkv, (const float4*)ow,
                                     (short4v*)wqkvb, (short4v*)owb);
  k_ln<<<8192, 256, 0, stream>>>(x, nw, nb, lnb);
  k_gemm<0><<<dim3(24, 64), 256, 0, stream>>>(lnb, wqkvb, bqkv, out, qkvh, 1024, 3072);
  k_vt<<<dim3(32, 16, 4), 256, 0, stream>>>(out + 2 * (size_t)BSH, vt);
  k_attn<<<1024, 256, 0, stream>>>(qkvh, mask, out + 3 * (size_t)BSH, lnb);
  k_gemm<1><<<dim3(8, 64), 256, 0, stream>>>(lnb, owb, nullptr, out, nullptr, 1024, 1024);
}

// Round 6
// 350.367 us; speedup vs baseline: 1.1941x; 1.0754x over previous
//
#include <hip/hip_runtime.h>
#include <cstdint>

// ---------------------------------------------------------------------------
// DeepSpeedSelfAttention fused: LN -> QKV GEMM -> flash attention -> out proj
// B=4 S=2048 H=1024 HEADS=16 DHEAD=64. bf16 MFMA 16x16x32 everywhere.
// R9: k_gemm rebuilt. R8 counters: k_gemm<0> is now the largest kernel
// (94.8us, 543 TF, MfmaUtil 22.8) -- the 128x128/BK=32 2-barrier structure's
// ceiling. New structure: 256x128 tile, BK=64, 512 threads (8 waves 4Mx2N),
// single-barrier double-buffered K-loop (the k_attn loop shape, verified
// conflict-free this session): barrier; stage(kt+1 -> other buf, 6x
// global_load_lds dwordx4/thread); 32 MFMA vs 16 ds_read_b128 per wave.
// Loads stay in flight across the whole compute phase (no vmcnt drain
// between stage and MFMA). LDS 96KB -> 1 block/CU, 2 waves/SIMD. Grid fits
// exactly: MODE0 24x32=768=3 rounds, MODE1 8x32=256=1 round. Same 8-row-XOR
// swizzle family as k_attn (pre-swizzled global source + XOR ds_read).
// k_attn / k_ln / k_vt / k_convert unchanged from R8 (verified).
// Outputs: [0] out_proj [1] key [2] value [3] context (f32 each).
// ---------------------------------------------------------------------------

typedef __attribute__((ext_vector_type(8))) short short8;
typedef __attribute__((ext_vector_type(4))) short short4v;
typedef __attribute__((ext_vector_type(4))) float floatx4;

#define BSH 8388608
#define PART_STRIDE 8388608
#define LOG2E 1.4426950408889634f

static __device__ __forceinline__ short f2bf(float f) {  // RNE
  union { float f; uint32_t u; } v; v.f = f;
  uint32_t r = v.u + 0x7fffu + ((v.u >> 16) & 1u);
  return (short)(r >> 16);
}

// async global->LDS, width 16. LDS dest = wave-uniform base + lane*16.
typedef __attribute__((address_space(1))) void gas_t;
typedef __attribute__((address_space(3))) void las_t;
static __device__ __forceinline__ void async16(const void* g, const void* l) {
  __builtin_amdgcn_global_load_lds((gas_t*)(uintptr_t)g,
                                   (las_t*)(uint32_t)(uintptr_t)l, 16, 0, 0);
}

// pack 2 f32 -> 1 dword of 2 bf16 (lo = a, hi = b)
static __device__ __forceinline__ uint32_t cvt_pk_bf16(float a, float b) {
  uint32_t r;
  asm("v_cvt_pk_bf16_f32 %0, %1, %2" : "=v"(r) : "v"(a), "v"(b));
  return r;
}
// vdst lanes[32:63] <-> vsrc lanes[0:31]
static __device__ __forceinline__ void swap32(uint32_t& a, uint32_t& b) {
  asm("v_permlane32_swap_b32 %0, %1" : "+v"(a), "+v"(b));
}
// vdst odd 16-rows <-> vsrc even 16-rows (16-31<->0-15, 48-63<->32-47)
static __device__ __forceinline__ void swap16(uint32_t& a, uint32_t& b) {
  asm("v_permlane16_swap_b32 %0, %1" : "+v"(a), "+v"(b));
}
static __device__ __forceinline__ short8 s8_from(uint32_t a, uint32_t b,
                                                 uint32_t c, uint32_t d) {
  union { uint32_t u[4]; short8 s; } t;
  t.u[0] = a; t.u[1] = b; t.u[2] = c; t.u[3] = d;
  return t.s;
}

// ---- fp32 -> bf16 weight conversion ---------------------------------------
__global__ __launch_bounds__(256) void k_convert(const float4* __restrict__ wqkv,
                                                 const float4* __restrict__ ow,
                                                 short4v* __restrict__ dq,
                                                 short4v* __restrict__ dow) {
  const int n1 = (3072 * 1024) / 4, n2 = (1024 * 1024) / 4;
  for (int i = blockIdx.x * 256 + threadIdx.x; i < n1 + n2; i += gridDim.x * 256) {
    float4 v = (i < n1) ? wqkv[i] : ow[i - n1];
    short4v s;
    s[0] = f2bf(v.x); s[1] = f2bf(v.y); s[2] = f2bf(v.z); s[3] = f2bf(v.w);
    if (i < n1) dq[i] = s; else dow[i - n1] = s;
  }
}

// ---- LayerNorm: one block per row of 1024, bf16 out ------------------------
__global__ __launch_bounds__(256) void k_ln(const float* __restrict__ x,
                                            const float* __restrict__ w,
                                            const float* __restrict__ bb,
                                            short* __restrict__ out) {
  const int row = blockIdx.x, t = threadIdx.x;
  float4 v = ((const float4*)(x + row * 1024))[t];
  float s = v.x + v.y + v.z + v.w;
  float sq = v.x * v.x + v.y * v.y + v.z * v.z + v.w * v.w;
#pragma unroll
  for (int off = 32; off; off >>= 1) { s += __shfl_down(s, off); sq += __shfl_down(sq, off); }
  __shared__ float ls[4], lq[4];
  if ((t & 63) == 0) { ls[t >> 6] = s; lq[t >> 6] = sq; }
  __syncthreads();
  s = ls[0] + ls[1] + ls[2] + ls[3];
  sq = lq[0] + lq[1] + lq[2] + lq[3];
  float mu = s * (1.0f / 1024.0f);
  float var = sq * (1.0f / 1024.0f) - mu * mu;
  float rs = rsqrtf(fmaxf(var, 0.0f) + 1e-12f);
  float4 wv = ((const float4*)w)[t];
  float4 bv = ((const float4*)bb)[t];
  short4v o;
  o[0] = f2bf((v.x - mu) * rs * wv.x + bv.x);
  o[1] = f2bf((v.y - mu) * rs * wv.y + bv.y);
  o[2] = f2bf((v.z - mu) * rs * wv.z + bv.z);
  o[3] = f2bf((v.w - mu) * rs * wv.w + bv.w);
  ((short4v*)out)[row * 256 + t] = o;
}

// ---- bf16 GEMM C[M,N] = A[M,K] @ Bm[N,K]^T, 256x128x64, 512 thr, 8 waves ---
// Single-barrier double-buffered K-loop; per K-tile per wave: 32 MFMA,
// 16 ds_read_b128; staging = 6 async16/thread into the inactive buffer.
// MODE 0: QKV epilogue. q: bf16 head-layout pre-scaled by 0.125*log2e.
//         k: bf16 head-layout + fp32 out[1]. v: fp32 out[2] ONLY (coalesced;
//         transpose handled by k_vt). MODE 1: plain fp32 store.
template <int MODE>
__global__ __launch_bounds__(512, 2) void k_gemm(const short* __restrict__ A,
                                                 const short* __restrict__ Bm,
                                                 const float* __restrict__ bias,
                                                 float* __restrict__ out,
                                                 short* __restrict__ qkvh,
                                                 int K, int N) {
  __shared__ short As[2][256 * 64];   // 2 x 32 KB
  __shared__ short Bs[2][128 * 64];   // 2 x 16 KB
  const int tid = threadIdx.x, lane = tid & 63, w = tid >> 6;
  const int quad = lane >> 4, l15 = lane & 15;
  const int wm = w >> 1, wn = w & 1;             // 4 M-waves x 2 N-waves
  const int m0 = blockIdx.y * 256, n0 = blockIdx.x * 128;
  const int srow = tid >> 3;                     // [0,64) staging row in unit
  const int sc8 = (tid & 7) ^ (srow & 7);        // pre-swizzled 16B chunk

  floatx4 acc[4][4] = {};

  auto stage = [&](int kt, int bi) {
    const short* asrc = &A[(size_t)(m0 + srow) * K + kt * 64 + sc8 * 8];
#pragma unroll
    for (int u = 0; u < 4; u++)                  // A: 4 units of 64 rows
      async16(asrc + (size_t)u * 64 * K, &As[bi][u * 4096 + tid * 8]);
    const short* bsrc = &Bm[(size_t)(n0 + srow) * K + kt * 64 + sc8 * 8];
#pragma unroll
    for (int u = 0; u < 2; u++)                  // B: 2 units of 64 rows
      async16(bsrc + (size_t)u * 64 * K, &Bs[bi][u * 4096 + tid * 8]);
  };

  stage(0, 0);
  const int NT = K >> 6;                         // 16 K-tiles
  for (int kt = 0; kt < NT; kt++) {
    const int cur = kt & 1;
    __syncthreads();                             // buf[cur] resident
    if (kt + 1 < NT) stage(kt + 1, cur ^ 1);
#pragma unroll
    for (int ks = 0; ks < 2; ks++) {
      short8 af[4], bf[4];
#pragma unroll
      for (int m = 0; m < 4; m++) {
        const int r = wm * 64 + m * 16 + l15;
        af[m] = *(const short8*)&As[cur][r * 64 + (((ks * 4 + quad) ^ (r & 7)) * 8)];
      }
#pragma unroll
      for (int n = 0; n < 4; n++) {
        const int r = wn * 64 + n * 16 + l15;
        bf[n] = *(const short8*)&Bs[cur][r * 64 + (((ks * 4 + quad) ^ (r & 7)) * 8)];
      }
#pragma unroll
      for (int m = 0; m < 4; m++)
#pragma unroll
        for (int n = 0; n < 4; n++)
          acc[m][n] = __builtin_amdgcn_mfma_f32_16x16x32_bf16(af[m], bf[n], acc[m][n], 0, 0, 0);
    }
  }

  const int grB = m0 + wm * 64, gcB = n0 + wn * 64;
  const float QS = 0.125f * LOG2E;
#pragma unroll
  for (int m = 0; m < 4; m++) {
#pragma unroll
    for (int n = 0; n < 4; n++) {
      int gc = gcB + n * 16 + l15;
      if (MODE == 0) {
        float bv = bias[gc];
        int part = gc >> 10, within = gc & 1023;
        int head = within >> 6, dd = within & 63;
#pragma unroll
        for (int reg = 0; reg < 4; reg++) {
          int gr = grB + m * 16 + quad * 4 + reg;
          float val = acc[m][n][reg] + bv;
          int b_ = gr >> 11, s_ = gr & 2047;
          int hs = (b_ * 16 + head);
          if (part == 0) {
            qkvh[(hs * 2048 + s_) * 64 + dd] = f2bf(val * QS);
          } else if (part == 1) {
            qkvh[PART_STRIDE + (hs * 2048 + s_) * 64 + dd] = f2bf(val);
            out[BSH + gr * 1024 + within] = val;
          } else {
            out[2 * BSH + gr * 1024 + within] = val;
          }
        }
      } else {
#pragma unroll
        for (int reg = 0; reg < 4; reg++) {
          int gr = grB + m * 16 + quad * 4 + reg;
          out[gr * N + gc] = acc[m][n][reg];
        }
      }
    }
  }
}

// ---- V transpose: fp32 [b][s][h*64+d] -> bf16 [b*16+h][d][s] ---------------
// One block per (64-s-tile, h, b). L2-warm reads (just written by k_gemm<0>).
__global__ __launch_bounds__(256) void k_vt(const float* __restrict__ vsrc,
                                            short* __restrict__ vt) {
  const int st = blockIdx.x, h = blockIdx.y, b = blockIdx.z;
  const int t = threadIdx.x;
  __shared__ short Ls[64 * 64];
  const int s0 = st * 64;
#pragma unroll
  for (int j = 0; j < 4; j++) {
    int flat = j * 1024 + t * 4;
    int sl = flat >> 6, d = flat & 63;
    float4 v4 = *(const float4*)&vsrc[(size_t)(b * 2048 + s0 + sl) * 1024 + h * 64 + d];
    short4v s4;
    s4[0] = f2bf(v4.x); s4[1] = f2bf(v4.y); s4[2] = f2bf(v4.z); s4[3] = f2bf(v4.w);
    *(short4v*)&Ls[sl * 64 + (((d >> 3) ^ (sl & 7)) * 8) + (d & 7)] = s4;
  }
  __syncthreads();
  const int d = t >> 2, sbase = (t & 3) * 16;
#pragma unroll
  for (int half = 0; half < 2; half++) {
    short8 o;
#pragma unroll
    for (int j = 0; j < 8; j++) {
      int s = sbase + half * 8 + j;
      o[j] = Ls[s * 64 + (((d >> 3) ^ (s & 7)) * 8) + (d & 7)];
    }
    *(short8*)&vt[(size_t)((b * 16 + h) * 64 + d) * 2048 + s0 + sbase + half * 8] = o;
  }
}

// ---- flash attention (R8, verified): 1D grid 1024, XCD-swizzled ------------
// wid = (bid&7)*128 + (bid>>3): each XCD owns 8 complete (h,b) pairs x 16 qt
// tiles; per-XCD K/V set = 4MB = L2. Swapped QK^T, in-register P routing
// (cvt_pk + permlane swaps), no online max, ones-MFMA row sums.
__global__ __launch_bounds__(256, 4) void k_attn(const short* __restrict__ qkvh,
                                                 const float* __restrict__ mask,
                                                 float* __restrict__ ctx_out,
                                                 short* __restrict__ ctx_bf) {
  const int bid = blockIdx.x;
  const int wid = (bid & 7) * 128 + (bid >> 3);
  const int qt = wid & 15, h = (wid >> 4) & 15, b = wid >> 8;
  const int tid = threadIdx.x, lane = tid & 63, w = tid >> 6;
  const int quad = lane >> 4, l15 = lane & 15;
  __shared__ short Ks[2][64 * 64];
  __shared__ short Vt[2][64 * 64];
  const short* qg = qkvh + (size_t)(b * 16 + h) * 2048 * 64;
  const short* kg = qg + PART_STRIDE;
  const short* vg = qkvh + 2 * PART_STRIDE + (size_t)(b * 16 + h) * 64 * 2048;  // [d][s]
  const float* mb = mask + b * 2048;

  // Q fragments: 2 row-tiles x 2 d-halves (B-operand of the swapped MFMA)
  short8 qf[2][2];
#pragma unroll
  for (int rt = 0; rt < 2; rt++) {
    const int qr = qt * 128 + w * 32 + rt * 16 + l15;
#pragma unroll
    for (int ks = 0; ks < 2; ks++)
      qf[rt][ks] = *(const short8*)&qg[qr * 64 + ks * 32 + quad * 8];
  }

  short8 ones;
#pragma unroll
  for (int j = 0; j < 8; j++) ones[j] = (short)0x3F80;  // bf16 1.0

  floatx4 accO[2][4] = {};
  floatx4 accL[2] = {};

  auto stage = [&](int kt, int bi) {
#pragma unroll
    for (int r = 0; r < 2; r++) {
      int pb = r * 256 + w * 64;
      int p = pb + lane;
      int row = p >> 3, c = (p & 7) ^ (row & 7);
      async16(&kg[(kt * 64 + row) * 64 + c * 8], &Ks[bi][pb * 8]);
      async16(&vg[row * 2048 + kt * 64 + c * 8], &Vt[bi][pb * 8]);
    }
  };
  stage(0, 0);

  for (int kt = 0; kt < 32; kt++) {
    const int cur = kt & 1;
    __syncthreads();                     // buf[cur] resident; buf[cur^1] free
    if (kt + 1 < 32) stage(kt + 1, cur ^ 1);

    // mask: k on the reg axis -> vector float4 loads
    float mv[4][4];
#pragma unroll
    for (int nt = 0; nt < 4; nt++) {
      float4 t = *(const float4*)&mb[kt * 64 + nt * 16 + quad * 4];
      mv[nt][0] = t.x; mv[nt][1] = t.y; mv[nt][2] = t.z; mv[nt][3] = t.w;
    }

    // S^T = K Q^T  (16 MFMA, 8 kf reads shared across both row-tiles)
    floatx4 sc[2][4] = {};
#pragma unroll
    for (int nt = 0; nt < 4; nt++) {
      const int krow = nt * 16 + l15;
#pragma unroll
      for (int ks = 0; ks < 2; ks++) {
        short8 kf = *(const short8*)&Ks[cur][krow * 64 + (((ks * 4 + quad) ^ (krow & 7)) * 8)];
        sc[0][nt] = __builtin_amdgcn_mfma_f32_16x16x32_bf16(kf, qf[0][ks], sc[0][nt], 0, 0, 0);
        sc[1][nt] = __builtin_amdgcn_mfma_f32_16x16x32_bf16(kf, qf[1][ks], sc[1][nt], 0, 0, 0);
      }
    }

    // p = exp2(s + m*log2e) -> bf16 pack -> cross-quad routing in registers.
    // pa[rt][ks2][m]: A-frag dwords for PV.
    uint32_t pa[2][2][4];
#pragma unroll
    for (int rt = 0; rt < 2; rt++) {
#pragma unroll
      for (int e = 0; e < 2; e++) {
#pragma unroll
        for (int d = 0; d < 2; d++) {
          float p0 = __builtin_amdgcn_exp2f(fmaf(mv[2 * e][2 * d], LOG2E, sc[rt][2 * e][2 * d]));
          float p1 = __builtin_amdgcn_exp2f(fmaf(mv[2 * e][2 * d + 1], LOG2E, sc[rt][2 * e][2 * d + 1]));
          float p2 = __builtin_amdgcn_exp2f(fmaf(mv[2 * e + 1][2 * d], LOG2E, sc[rt][2 * e + 1][2 * d]));
          float p3 = __builtin_amdgcn_exp2f(fmaf(mv[2 * e + 1][2 * d + 1], LOG2E, sc[rt][2 * e + 1][2 * d + 1]));
          uint32_t rE = cvt_pk_bf16(p0, p1);  // X[2e][d]
          uint32_t rO = cvt_pk_bf16(p2, p3);  // X[2e+1][d]
          swap32(rE, rO);
          swap16(rE, rO);
          pa[rt][e][d] = rE;      // A[ks2=e][m=d]
          pa[rt][e][2 + d] = rO;  // A[ks2=e][m=2+d]
        }
      }
    }

    // O += P V ; L += P 1  (20 MFMA, 8 vf reads shared across row-tiles)
#pragma unroll
    for (int ks2 = 0; ks2 < 2; ks2++) {
      short8 pf0 = s8_from(pa[0][ks2][0], pa[0][ks2][1], pa[0][ks2][2], pa[0][ks2][3]);
      short8 pf1 = s8_from(pa[1][ks2][0], pa[1][ks2][1], pa[1][ks2][2], pa[1][ks2][3]);
      accL[0] = __builtin_amdgcn_mfma_f32_16x16x32_bf16(pf0, ones, accL[0], 0, 0, 0);
      accL[1] = __builtin_amdgcn_mfma_f32_16x16x32_bf16(pf1, ones, accL[1], 0, 0, 0);
#pragma unroll
      for (int nt2 = 0; nt2 < 4; nt2++) {
        const int vrow = nt2 * 16 + l15;
        short8 vf = *(const short8*)&Vt[cur][vrow * 64 + (((ks2 * 4 + quad) ^ (vrow & 7)) * 8)];
        accO[0][nt2] = __builtin_amdgcn_mfma_f32_16x16x32_bf16(pf0, vf, accO[0][nt2], 0, 0, 0);
        accO[1][nt2] = __builtin_amdgcn_mfma_f32_16x16x32_bf16(pf1, vf, accO[1][nt2], 0, 0, 0);
      }
    }
  }

  // epilogue: divide by row sums; fp32 -> d_out slice 3, bf16 -> ws
#pragma unroll
  for (int rt = 0; rt < 2; rt++) {
    float inv[4];
#pragma unroll
    for (int reg = 0; reg < 4; reg++) inv[reg] = 1.0f / accL[rt][reg];
#pragma unroll
    for (int nt2 = 0; nt2 < 4; nt2++)
#pragma unroll
      for (int reg = 0; reg < 4; reg++) {
        const int qrow = qt * 128 + w * 32 + rt * 16 + quad * 4 + reg;
        const int col = h * 64 + nt2 * 16 + l15;
        const int gi = (b * 2048 + qrow) * 1024 + col;
        float val = accO[rt][nt2][reg] * inv[reg];
        ctx_out[gi] = val;
        ctx_bf[gi] = f2bf(val);
      }
  }
}

// ---------------------------------------------------------------------------
extern "C" void kernel_launch(void* const* d_in, const int* in_sizes, int n_in,
                              void* d_out, int out_size, void* d_ws, size_t ws_size,
                              hipStream_t stream) {
  const float* x    = (const float*)d_in[0];
  const float* mask = (const float*)d_in[1];
  const float* nw   = (const float*)d_in[2];
  const float* nb   = (const float*)d_in[3];
  const float* wqkv = (const float*)d_in[4];
  const float* bqkv = (const float*)d_in[5];
  const float* ow   = (const float*)d_in[6];
  float* out = (float*)d_out;
  char* ws = (char*)d_ws;

  // ws layout (bytes): [0,16M) ln_bf16 (aliased later as ctx_bf16);
  // [16M,22.3M) wqkv bf16; [22.3M,24M) ow bf16;
  // [24M,+16M) q head-layout; [+16M,+32M) k head-layout; [+32M,+48M) v^T
  short* lnb   = (short*)ws;
  short* wqkvb = (short*)(ws + 16777216);
  short* owb   = (short*)(ws + 23068672);
  short* qkvh  = (short*)(ws + 25165824);
  short* vt    = qkvh + 2 * (size_t)PART_STRIDE;

  k_convert<<<512, 256, 0, stream>>>((const float4*)wqkv, (const float4*)ow,
                                     (short4v*)wqkvb, (short4v*)owb);
  k_ln<<<8192, 256, 0, stream>>>(x, nw, nb, lnb);
  k_gemm<0><<<dim3(24, 32), 512, 0, stream>>>(lnb, wqkvb, bqkv, out, qkvh, 1024, 3072);
  k_vt<<<dim3(32, 16, 4), 256, 0, stream>>>(out + 2 * (size_t)BSH, vt);
  k_attn<<<1024, 256, 0, stream>>>(qkvh, mask, out + 3 * (size_t)BSH, lnb);
  k_gemm<1><<<dim3(8, 32), 512, 0, stream>>>(lnb, owb, nullptr, out, nullptr, 1024, 1024);
}